// Round 3
// baseline (115.557 us; speedup 1.0000x reference)
//
#include <hip/hip_runtime.h>
#include <hip/hip_bf16.h>
#include <math.h>

#define NN 4096
#define DD 256
#define TWO_N 8192
#define SCALE 14.426950408889634f   // (1/T)*log2(e)
#define INV_2N (1.0f/8192.0f)

typedef __bf16 bf16_t;
typedef bf16_t bf16x8 __attribute__((ext_vector_type(8)));
typedef bf16_t bf16x4 __attribute__((ext_vector_type(4)));
typedef float f32x4 __attribute__((ext_vector_type(4)));

// ---------------- normalize rows -> bf16 Zn ; zero rowsum/possum/out ----------------
__global__ __launch_bounds__(256) void knorm(const float* __restrict__ zi,
                                             const float* __restrict__ zj,
                                             bf16_t* __restrict__ zn,
                                             float* __restrict__ rowsum,
                                             float* __restrict__ possum,
                                             float* __restrict__ out) {
    const int wid = threadIdx.x >> 6, lane = threadIdx.x & 63;
    const int b = blockIdx.x;
    if (b < 8) {                                   // zero rowsum[8192] + scalars
        f32x4 z = {0, 0, 0, 0};
        *(f32x4*)(rowsum + b * 1024 + threadIdx.x * 4) = z;
        if (b == 0 && threadIdx.x == 0) { possum[0] = 0.0f; out[0] = 0.0f; }
    }
    const int row = b * 4 + wid;                   // grid = 2048 -> rows 0..8191
    const float* src = (row < NN) ? (zi + (size_t)row * DD)
                                  : (zj + (size_t)(row - NN) * DD);
    float4 v = *(const float4*)(src + lane * 4);
    float ss = v.x*v.x + v.y*v.y + v.z*v.z + v.w*v.w;
    #pragma unroll
    for (int m = 1; m < 64; m <<= 1) ss += __shfl_xor(ss, m);
    const float sc = 1.0f / fmaxf(sqrtf(ss), 1e-8f);
    bf16x4 o;
    o[0] = (bf16_t)(v.x * sc);
    o[1] = (bf16_t)(v.y * sc);
    o[2] = (bf16_t)(v.z * sc);
    o[3] = (bf16_t)(v.w * sc);
    *(bf16x4*)(zn + (size_t)row * DD + lane * 4) = o;
}

// ---------------- main: upper-triangular 128x128 tiles of exp(sim/T) ----------------
// grid = 2080 (= 64*65/2) blocks, 256 threads (4 waves in 2x2), K=256 in 4 steps of 64.
// T3 2-phase pipeline: double-buffered LDS, counted vmcnt, raw barriers.
__global__ __launch_bounds__(256, 2) void kmain(const bf16_t* __restrict__ zn,
                                                float* __restrict__ rowsum,
                                                float* __restrict__ possum) {
    __shared__ char ldsA[2][16384];   // [128 rows][64 bf16 = 128 B], XOR-swizzled
    __shared__ char ldsB[2][16384];
    const int tid = threadIdx.x, wid = tid >> 6, lane = tid & 63;

    // triangular decode (uniform scalar loop)
    int ti = 0, rem = blockIdx.x;
    while (rem >= 64 - ti) { rem -= 64 - ti; ++ti; }
    const int tj = ti + rem;
    const int rowbase = ti << 7, colbase = tj << 7;

    const int wr = wid >> 1, wc = wid & 1;         // 2x2 wave grid, 64x64 each
    const int lo = lane & 15, hi = lane >> 4;

    f32x4 acc[4][4];
    #pragma unroll
    for (int s = 0; s < 4; ++s)
        #pragma unroll
        for (int t = 0; t < 4; ++t) acc[s][t] = (f32x4){0, 0, 0, 0};

    const char* gz = (const char*)zn;              // zn rows are 512 bytes

    // stage A+B 128x64 tiles for K-step ks into buffer buf: linear LDS dest
    // (wave-uniform base + lane*16), inverse-XOR-swizzled per-lane global source.
    // 8 global_load_lds per thread per call.
    auto stage = [&](int buf, int ks) {
        #pragma unroll
        for (int p = 0; p < 4; ++p) {
            const int base = p * 4096 + wid * 1024;          // wave-uniform
            const int dd   = base + lane * 16;               // what HW writes
            const int row  = dd >> 7, col = dd & 127;
            const int scol = col ^ ((row & 7) << 4);
            const char* ga = gz + (size_t)(rowbase + row) * 512 + ks * 128 + scol;
            const char* gb = gz + (size_t)(colbase + row) * 512 + ks * 128 + scol;
            __builtin_amdgcn_global_load_lds(
                (const __attribute__((address_space(1))) void*)ga,
                (__attribute__((address_space(3))) void*)(&ldsA[buf][base]), 16, 0, 0);
            __builtin_amdgcn_global_load_lds(
                (const __attribute__((address_space(1))) void*)gb,
                (__attribute__((address_space(3))) void*)(&ldsB[buf][base]), 16, 0, 0);
        }
    };

    stage(0, 0);                                   // prologue

    for (int ks = 0; ks < 4; ++ks) {
        const int cur = ks & 1;
        if (ks < 3) {
            stage(cur ^ 1, ks + 1);                // prefetch next K-step
            // wait only for the CURRENT tile's 8 loads; next tile's 8 stay in flight
            asm volatile("s_waitcnt vmcnt(8)" ::: "memory");
        } else {
            asm volatile("s_waitcnt vmcnt(0)" ::: "memory");
        }
        __builtin_amdgcn_s_barrier();              // all waves' cur-tile loads done

        #pragma unroll
        for (int kk = 0; kk < 2; ++kk) {
            bf16x8 af[4], bfr[4];
            const int kb = kk * 64 + hi * 16;
            const int sw = kb ^ ((lo & 7) << 4);   // swizzled k-offset
            #pragma unroll
            for (int s = 0; s < 4; ++s) {
                af[s]  = *(const bf16x8*)(&ldsA[cur][(wr * 64 + s * 16 + lo) * 128 + sw]);
                bfr[s] = *(const bf16x8*)(&ldsB[cur][(wc * 64 + s * 16 + lo) * 128 + sw]);
            }
            #pragma unroll
            for (int s = 0; s < 4; ++s)
                #pragma unroll
                for (int t = 0; t < 4; ++t)
                    acc[s][t] = __builtin_amdgcn_mfma_f32_16x16x32_bf16(
                        af[s], bfr[t], acc[s][t], 0, 0, 0);
        }
        // lgkmcnt before MFMA guarantees all ds_reads of cur completed before
        // any wave passes this barrier; cur is overwritten only at ks+2's stage.
        if (ks < 3) __builtin_amdgcn_s_barrier();
    }

    // ---- positives: diagonal of tiles with tj == ti+32 (col = row + 4096) ----
    if (tj == ti + 32 && wr == wc) {
        const int j = lo - hi * 4;                 // C layout: col=lo, row=hi*4+j
        float p = 0.0f;
        if (j >= 0 && j < 4) {
            #pragma unroll
            for (int s = 0; s < 4; ++s) p += acc[s][s][j];
        }
        #pragma unroll
        for (int m = 1; m < 64; m <<= 1) p += __shfl_xor(p, m);
        if (lane == 0) atomicAdd(possum, p);
    }

    // ---- exp in place ----
    #pragma unroll
    for (int s = 0; s < 4; ++s)
        #pragma unroll
        for (int t = 0; t < 4; ++t)
            #pragma unroll
            for (int j = 0; j < 4; ++j)
                acc[s][t][j] = __builtin_amdgcn_exp2f(acc[s][t][j] * SCALE);

    // ---- row sums (always) ----
    #pragma unroll
    for (int s = 0; s < 4; ++s) {
        f32x4 rs = acc[s][0] + acc[s][1] + acc[s][2] + acc[s][3];
        #pragma unroll
        for (int j = 0; j < 4; ++j) {
            float v = rs[j];
            v += __shfl_xor(v, 1); v += __shfl_xor(v, 2);
            v += __shfl_xor(v, 4); v += __shfl_xor(v, 8);
            if (lo == 0)
                atomicAdd(&rowsum[rowbase + wr * 64 + s * 16 + hi * 4 + j], v);
        }
    }

    // ---- col sums (symmetric contribution; off-diagonal tiles only) ----
    if (ti != tj) {
        #pragma unroll
        for (int t = 0; t < 4; ++t) {
            float v = 0.0f;
            #pragma unroll
            for (int s = 0; s < 4; ++s)
                v += acc[s][t][0] + acc[s][t][1] + acc[s][t][2] + acc[s][t][3];
            v += __shfl_xor(v, 16); v += __shfl_xor(v, 32);
            if (hi == 0)
                atomicAdd(&rowsum[colbase + wc * 64 + t * 16 + lo], v);
        }
    }
}

// ---------------- final: logs + scalar reduction ----------------
__global__ __launch_bounds__(256) void kfinal(const float* __restrict__ rowsum,
                                              const float* __restrict__ possum,
                                              float* __restrict__ out) {
    __shared__ float red[4];
    const int wid = threadIdx.x >> 6, lane = threadIdx.x & 63;
    const int gid = blockIdx.x * 256 + threadIdx.x;      // grid = 32 -> 8192 rows
    float v = logf(rowsum[gid] * INV_2N);
    #pragma unroll
    for (int m = 1; m < 64; m <<= 1) v += __shfl_xor(v, m);
    if (lane == 0) red[wid] = v;
    __syncthreads();
    if (threadIdx.x == 0) {
        float s = red[0] + red[1] + red[2] + red[3];
        if (blockIdx.x == 0) s -= 20.0f * possum[0];     // (1/T)*sum(pos), pos counted twice
        atomicAdd(out, s * INV_2N);
    }
}

extern "C" void kernel_launch(void* const* d_in, const int* in_sizes, int n_in,
                              void* d_out, int out_size, void* d_ws, size_t ws_size,
                              hipStream_t stream) {
    const float* zi = (const float*)d_in[0];
    const float* zj = (const float*)d_in[1];
    bf16_t* zn     = (bf16_t*)d_ws;                                   // 4 MB
    float*  rowsum = (float*)((char*)d_ws + (size_t)TWO_N * DD * 2);  // 32 KB
    float*  possum = rowsum + TWO_N;
    float*  out    = (float*)d_out;

    knorm <<<2048, 256, 0, stream>>>(zi, zj, zn, rowsum, possum, out);
    kmain <<<2080, 256, 0, stream>>>(zn, rowsum, possum);
    kfinal<<<32,   256, 0, stream>>>(rowsum, possum, out);
}

// Round 4
// 106.156 us; speedup vs baseline: 1.0886x; 1.0886x over previous
//
#include <hip/hip_runtime.h>
#include <hip/hip_bf16.h>
#include <math.h>

#define NN 4096
#define DD 256
#define TWO_N 8192
#define SCALE 14.426950408889634f   // (1/T)*log2(e)
#define INV_2N (1.0f/8192.0f)

typedef __bf16 bf16_t;
typedef bf16_t bf16x8 __attribute__((ext_vector_type(8)));
typedef bf16_t bf16x4 __attribute__((ext_vector_type(4)));
typedef float f32x4 __attribute__((ext_vector_type(4)));

// ---------------- normalize rows -> bf16 Zn ; zero possum/out ----------------
__global__ __launch_bounds__(256) void knorm(const float* __restrict__ zi,
                                             const float* __restrict__ zj,
                                             bf16_t* __restrict__ zn,
                                             float* __restrict__ possum,
                                             float* __restrict__ out) {
    const int wid = threadIdx.x >> 6, lane = threadIdx.x & 63;
    const int b = blockIdx.x;
    if (b == 0 && threadIdx.x == 0) { possum[0] = 0.0f; out[0] = 0.0f; }
    const int row = b * 4 + wid;                   // grid = 2048 -> rows 0..8191
    const float* src = (row < NN) ? (zi + (size_t)row * DD)
                                  : (zj + (size_t)(row - NN) * DD);
    float4 v = *(const float4*)(src + lane * 4);
    float ss = v.x*v.x + v.y*v.y + v.z*v.z + v.w*v.w;
    #pragma unroll
    for (int m = 1; m < 64; m <<= 1) ss += __shfl_xor(ss, m);
    const float sc = 1.0f / fmaxf(sqrtf(ss), 1e-8f);
    bf16x4 o;
    o[0] = (bf16_t)(v.x * sc);
    o[1] = (bf16_t)(v.y * sc);
    o[2] = (bf16_t)(v.z * sc);
    o[3] = (bf16_t)(v.w * sc);
    *(bf16x4*)(zn + (size_t)row * DD + lane * 4) = o;
}

// ---------------- main: upper-triangular 128x128 tiles of exp(sim/T) ----------------
// grid = 2080 (= 64*65/2) blocks, 256 threads (4 waves in 2x2), K=256 in 4 steps of 64.
// Round-2 GEMM core (best measured). Epilogue: NO contended atomics — unique
// per-(block,wave) partial-sum slots in PR/PC, gathered by kfinal.
__global__ __launch_bounds__(256, 4) void kmain(const bf16_t* __restrict__ zn,
                                                float* __restrict__ PR,
                                                float* __restrict__ PC,
                                                float* __restrict__ possum) {
    __shared__ char ldsA[16384];     // [128 rows][64 bf16 = 128 B], XOR-swizzled
    __shared__ char ldsB[16384];
    const int tid = threadIdx.x, wid = tid >> 6, lane = tid & 63;

    // bijective XCD swizzle: 2080 = 8 * 260 -> each XCD gets a contiguous arc
    const int bid = (int)blockIdx.x;
    const int wg  = (bid & 7) * 260 + (bid >> 3);

    // triangular decode (uniform scalar loop)
    int ti = 0, rem = wg;
    while (rem >= 64 - ti) { rem -= 64 - ti; ++ti; }
    const int tj = ti + rem;
    const int rowbase = ti << 7, colbase = tj << 7;

    const int wr = wid >> 1, wc = wid & 1;         // 2x2 wave grid, 64x64 each
    const int lo = lane & 15, hi = lane >> 4;

    f32x4 acc[4][4];
    #pragma unroll
    for (int s = 0; s < 4; ++s)
        #pragma unroll
        for (int t = 0; t < 4; ++t) acc[s][t] = (f32x4){0, 0, 0, 0};

    const char* gz = (const char*)zn;              // zn rows are 512 bytes

    for (int ks = 0; ks < 4; ++ks) {
        // stage A and B 128x64 tiles: linear LDS dest (wave-uniform base),
        // inverse-XOR-swizzled per-lane global source (both-sides rule)
        #pragma unroll
        for (int p = 0; p < 4; ++p) {
            const int base = p * 4096 + wid * 1024;          // wave-uniform
            const int dd   = base + lane * 16;               // what HW writes
            const int row  = dd >> 7, col = dd & 127;
            const int scol = col ^ ((row & 7) << 4);
            const char* ga = gz + (size_t)(rowbase + row) * 512 + ks * 128 + scol;
            const char* gb = gz + (size_t)(colbase + row) * 512 + ks * 128 + scol;
            __builtin_amdgcn_global_load_lds(
                (const __attribute__((address_space(1))) void*)ga,
                (__attribute__((address_space(3))) void*)(&ldsA[base]), 16, 0, 0);
            __builtin_amdgcn_global_load_lds(
                (const __attribute__((address_space(1))) void*)gb,
                (__attribute__((address_space(3))) void*)(&ldsB[base]), 16, 0, 0);
        }
        __syncthreads();                           // drains vmcnt -> tiles visible

        #pragma unroll
        for (int kk = 0; kk < 2; ++kk) {
            bf16x8 af[4], bfr[4];
            const int kb = kk * 64 + hi * 16;
            const int sw = kb ^ ((lo & 7) << 4);   // swizzled k-offset
            #pragma unroll
            for (int s = 0; s < 4; ++s) {
                af[s]  = *(const bf16x8*)(&ldsA[(wr * 64 + s * 16 + lo) * 128 + sw]);
                bfr[s] = *(const bf16x8*)(&ldsB[(wc * 64 + s * 16 + lo) * 128 + sw]);
            }
            #pragma unroll
            for (int s = 0; s < 4; ++s)
                #pragma unroll
                for (int t = 0; t < 4; ++t)
                    acc[s][t] = __builtin_amdgcn_mfma_f32_16x16x32_bf16(
                        af[s], bfr[t], acc[s][t], 0, 0, 0);
        }
        __syncthreads();                           // done reading before next stage
    }

    // ---- positives: diagonal of tiles with tj == ti+32 (col = row + 4096) ----
    if (tj == ti + 32 && wr == wc) {
        const int j = lo - hi * 4;                 // C layout: col=lo, row=hi*4+j
        float p = 0.0f;
        if (j >= 0 && j < 4) {
            #pragma unroll
            for (int s = 0; s < 4; ++s) p += acc[s][s][j];
        }
        #pragma unroll
        for (int m = 1; m < 64; m <<= 1) p += __shfl_xor(p, m);
        if (lane == 0) atomicAdd(possum, p);
    }

    // ---- snap self-similarity diagonal to exactly 1.0 (kills bf16 diag error) ----
    if (ti == tj && wr == wc) {
        const int j = lo - hi * 4;
        if (j >= 0 && j < 4) {
            #pragma unroll
            for (int s = 0; s < 4; ++s) acc[s][s][j] = 1.0f;
        }
    }

    // ---- exp in place ----
    #pragma unroll
    for (int s = 0; s < 4; ++s)
        #pragma unroll
        for (int t = 0; t < 4; ++t)
            #pragma unroll
            for (int j = 0; j < 4; ++j)
                acc[s][t][j] = __builtin_amdgcn_exp2f(acc[s][t][j] * SCALE);

    // ---- row partial sums -> PR[ti][tj][wc][wr*64 + r]  (plain stores) ----
    {
        float* PRb = PR + (((size_t)(ti * 64 + tj) * 2 + wc) << 7) + wr * 64;
        #pragma unroll
        for (int s = 0; s < 4; ++s) {
            f32x4 rs = acc[s][0] + acc[s][1] + acc[s][2] + acc[s][3];
            #pragma unroll
            for (int j = 0; j < 4; ++j) {
                float v = rs[j];
                v += __shfl_xor(v, 1); v += __shfl_xor(v, 2);
                v += __shfl_xor(v, 4); v += __shfl_xor(v, 8);
                if (lo == 0) PRb[s * 16 + hi * 4 + j] = v;
            }
        }
    }

    // ---- col partial sums -> PC[tj][ti][wr][wc*64 + c]  (off-diagonal only) ----
    if (ti != tj) {
        float* PCb = PC + (((size_t)(tj * 64 + ti) * 2 + wr) << 7) + wc * 64;
        #pragma unroll
        for (int t = 0; t < 4; ++t) {
            float v = 0.0f;
            #pragma unroll
            for (int s = 0; s < 4; ++s)
                v += acc[s][t][0] + acc[s][t][1] + acc[s][t][2] + acc[s][t][3];
            v += __shfl_xor(v, 16); v += __shfl_xor(v, 32);
            if (hi == 0) PCb[t * 16 + lo] = v;
        }
    }
}

// ---------------- final: gather partials, logs, scalar reduction ----------------
// grid = 64 blocks (one per tile-row a) x 128 threads (one per row in tile).
// Reads ONLY written slots: PR[a][t>=a][*][rr], PC[a][b<a][*][rr] -> 128 loads/thread.
__global__ __launch_bounds__(128) void kfinal(const float* __restrict__ PR,
                                              const float* __restrict__ PC,
                                              const float* __restrict__ possum,
                                              float* __restrict__ out) {
    __shared__ float red[2];
    const int a = blockIdx.x;
    const int rr = threadIdx.x;                    // 0..127
    const int wid = threadIdx.x >> 6, lane = threadIdx.x & 63;
    float total = 0.0f;
    for (int t = a; t < 64; ++t) {
        total += PR[(((size_t)(a * 64 + t) * 2 + 0) << 7) + rr];
        total += PR[(((size_t)(a * 64 + t) * 2 + 1) << 7) + rr];
    }
    for (int b = 0; b < a; ++b) {
        total += PC[(((size_t)(a * 64 + b) * 2 + 0) << 7) + rr];
        total += PC[(((size_t)(a * 64 + b) * 2 + 1) << 7) + rr];
    }
    float v = logf(total * INV_2N);
    #pragma unroll
    for (int m = 1; m < 64; m <<= 1) v += __shfl_xor(v, m);
    if (lane == 0) red[wid] = v;
    __syncthreads();
    if (threadIdx.x == 0) {
        float s = red[0] + red[1];
        if (a == 0) s -= 20.0f * possum[0];        // (1/T)*sum(pos), pos counted twice
        atomicAdd(out, s * INV_2N);
    }
}

extern "C" void kernel_launch(void* const* d_in, const int* in_sizes, int n_in,
                              void* d_out, int out_size, void* d_ws, size_t ws_size,
                              hipStream_t stream) {
    const float* zi = (const float*)d_in[0];
    const float* zj = (const float*)d_in[1];
    bf16_t* zn     = (bf16_t*)d_ws;                                  // [0, 4MB)
    float*  PR     = (float*)((char*)d_ws + ((size_t)4 << 20));      // [4MB, 8MB)
    float*  PC     = (float*)((char*)d_ws + ((size_t)8 << 20));      // [8MB, 12MB)
    float*  possum = (float*)((char*)d_ws + ((size_t)12 << 20));
    float*  out    = (float*)d_out;

    knorm <<<2048, 256, 0, stream>>>(zi, zj, zn, possum, out);
    kmain <<<2080, 256, 0, stream>>>(zn, PR, PC, possum);
    kfinal<<<64,   128, 0, stream>>>(PR, PC, possum, out);
}